// Round 1
// baseline (269.898 us; speedup 1.0000x reference)
//
#include <hip/hip_runtime.h>
#include <stdint.h>

typedef __attribute__((ext_vector_type(8))) short bf16x8;
typedef __attribute__((ext_vector_type(4))) float f32x4;

#if __has_builtin(__builtin_amdgcn_exp2f)
#define EXP2F(x) __builtin_amdgcn_exp2f(x)
#else
#define EXP2F(x) exp2f(x)
#endif

__device__ __forceinline__ short f2bf(float f) {
    union { float f; uint32_t u; } c; c.f = f;
    return (short)((c.u + 0x7fffu + ((c.u >> 16) & 1u)) >> 16);
}

// ---- prep: Wt[192][512] bf16 (Wt[col][c] = W[c][col]; cols 0-63=K,64-127=Q,128-191=V), bcat[192] f32
__global__ void prep_kernel(const float* __restrict__ Wk, const float* __restrict__ bk,
                            const float* __restrict__ Wq, const float* __restrict__ bq,
                            const float* __restrict__ Wv, const float* __restrict__ bv,
                            short* __restrict__ Wt, float* __restrict__ bcat) {
    const int col = blockIdx.x;  // 0..191
    const float* W; const float* bb; int c0;
    if (col < 64)       { W = Wk; bb = bk; c0 = col; }
    else if (col < 128) { W = Wq; bb = bq; c0 = col - 64; }
    else                { W = Wv; bb = bv; c0 = col - 128; }
    for (int c = threadIdx.x; c < 512; c += blockDim.x)
        Wt[col * 512 + c] = f2bf(W[(size_t)c * 64 + c0]);
    if (threadIdx.x == 0) bcat[col] = bb[c0];
}

// ---- pass 1: fused QKV projection, 128 rows x 192 cols per block ----
__global__ __launch_bounds__(256, 2) void qkv_kernel(
    const float* __restrict__ x, const short* __restrict__ Wt,
    const float* __restrict__ bcat,
    short* __restrict__ Kb, short* __restrict__ Qb, short* __restrict__ Vb) {
    __shared__ __align__(16) short xb[2][128][40];  // stride 40 shorts = 80B: 16B-aligned rows, conflict-padded
    const int tid = threadIdx.x;
    const int wave = tid >> 6, lane = tid & 63;
    const int quad = lane >> 4, l16 = lane & 15;
    const int row0 = blockIdx.x * 128;

    f32x4 acc[2][12];
#pragma unroll
    for (int m = 0; m < 2; m++)
#pragma unroll
        for (int i = 0; i < 12; i++) acc[m][i] = (f32x4){0.f, 0.f, 0.f, 0.f};

    const int srow = tid >> 1;        // 0..127
    const int sseg = tid & 1;         // 16 floats each
    const float* xrow = x + (size_t)(row0 + srow) * 512 + sseg * 16;

    float4 g0 = ((const float4*)xrow)[0];
    float4 g1 = ((const float4*)xrow)[1];
    float4 g2 = ((const float4*)xrow)[2];
    float4 g3 = ((const float4*)xrow)[3];
    {
        bf16x8 p0, p1;
        p0[0]=f2bf(g0.x); p0[1]=f2bf(g0.y); p0[2]=f2bf(g0.z); p0[3]=f2bf(g0.w);
        p0[4]=f2bf(g1.x); p0[5]=f2bf(g1.y); p0[6]=f2bf(g1.z); p0[7]=f2bf(g1.w);
        p1[0]=f2bf(g2.x); p1[1]=f2bf(g2.y); p1[2]=f2bf(g2.z); p1[3]=f2bf(g2.w);
        p1[4]=f2bf(g3.x); p1[5]=f2bf(g3.y); p1[6]=f2bf(g3.z); p1[7]=f2bf(g3.w);
        *(bf16x8*)&xb[0][srow][sseg*16]     = p0;
        *(bf16x8*)&xb[0][srow][sseg*16 + 8] = p1;
    }
    __syncthreads();

    for (int c = 0; c < 16; c++) {
        const int buf = c & 1;
        if (c < 15) {
            const float4* nx = (const float4*)(xrow + (c + 1) * 32);
            g0 = nx[0]; g1 = nx[1]; g2 = nx[2]; g3 = nx[3];
        }
        bf16x8 af0 = *(const bf16x8*)&xb[buf][wave*32 + l16][quad*8];
        bf16x8 af1 = *(const bf16x8*)&xb[buf][wave*32 + 16 + l16][quad*8];
#pragma unroll
        for (int nt = 0; nt < 12; nt++) {
            bf16x8 bfrag = *(const bf16x8*)&Wt[(nt*16 + l16)*512 + c*32 + quad*8];
            acc[0][nt] = __builtin_amdgcn_mfma_f32_16x16x32_bf16(af0, bfrag, acc[0][nt], 0, 0, 0);
            acc[1][nt] = __builtin_amdgcn_mfma_f32_16x16x32_bf16(af1, bfrag, acc[1][nt], 0, 0, 0);
        }
        if (c < 15) {
            bf16x8 p0, p1;
            p0[0]=f2bf(g0.x); p0[1]=f2bf(g0.y); p0[2]=f2bf(g0.z); p0[3]=f2bf(g0.w);
            p0[4]=f2bf(g1.x); p0[5]=f2bf(g1.y); p0[6]=f2bf(g1.z); p0[7]=f2bf(g1.w);
            p1[0]=f2bf(g2.x); p1[1]=f2bf(g2.y); p1[2]=f2bf(g2.z); p1[3]=f2bf(g2.w);
            p1[4]=f2bf(g3.x); p1[5]=f2bf(g3.y); p1[6]=f2bf(g3.z); p1[7]=f2bf(g3.w);
            *(bf16x8*)&xb[buf^1][srow][sseg*16]     = p0;
            *(bf16x8*)&xb[buf^1][srow][sseg*16 + 8] = p1;
        }
        __syncthreads();
    }

    // epilogue: C layout row=(lane>>4)*4+reg, col=lane&15 (m89/m91-verified)
#pragma unroll
    for (int m = 0; m < 2; m++) {
        const int rowbase = row0 + wave*32 + m*16 + quad*4;
#pragma unroll
        for (int nt = 0; nt < 12; nt++) {
            const int col = nt*16 + l16;
            const float bias = bcat[col];
            short* dst = (nt < 4) ? Kb : (nt < 8) ? Qb : Vb;
            const int h = col & 63;
#pragma unroll
            for (int r = 0; r < 4; r++)
                dst[(size_t)(rowbase + r)*64 + h] = f2bf(acc[m][nt][r] + bias);
        }
    }
}

// ---- pass 2: causal attention, block = (q-tile j, batch b) ----
#define KSTR 72   // K row stride (shorts): 2-way banks (free), 16B-aligned rows
#define VSTR 72   // Vt row stride within 64-s chunk
#define PSTR 40   // per-wave P scratch row stride

__global__ __launch_bounds__(256, 2) void attn_kernel(
    const short* __restrict__ Kb, const short* __restrict__ Qb,
    const short* __restrict__ Vb, float* __restrict__ out) {
    __shared__ __align__(16) short Ks[256 * KSTR];     // 36864 B
    __shared__ __align__(16) short Vt[2][64 * VSTR];   // 18432 B (double-buffered V^T chunks)
    __shared__ __align__(16) short Ps[4][16 * PSTR];   // 5120 B  (per-wave P C->A layout roundtrip)

    const int j = blockIdx.x;          // q tile 0..3 (rows 64j..64j+63)
    const int b = blockIdx.y;
    const int tid = threadIdx.x;
    const int wave = tid >> 6, lane = tid & 63;
    const int quad = lane >> 4, l16 = lane & 15;
    const int ntiles = 4 * (j + 1);    // 16-wide s tiles needed (causal)
    const int nchunks = j + 1;         // 64-wide s chunks
    const size_t bbase = (size_t)b * (256 * 64);

    // Q fragments: A layout lane m=l16, k=quad*8+jj (m120-verified)
    const int qrow = j*64 + wave*16 + l16;
    const bf16x8 qf0 = *(const bf16x8*)&Qb[bbase + (size_t)qrow*64 + quad*8];
    const bf16x8 qf1 = *(const bf16x8*)&Qb[bbase + (size_t)qrow*64 + 32 + quad*8];

    // stage K rows [0, 64*(j+1))
    {
        const int r = tid >> 2, seg = tid & 3;
        for (int rb = 0; rb < nchunks; rb++) {
            const int row = rb*64 + r;
            const uint4* src = (const uint4*)&Kb[bbase + (size_t)row*64 + seg*16];
            uint4 a0 = src[0], a1 = src[1];
            *(uint4*)&Ks[row*KSTR + seg*16]     = a0;
            *(uint4*)&Ks[row*KSTR + seg*16 + 8] = a1;
        }
    }
    // stage V chunk 0, transposed: Vt[h][s]; packed pair writes (s even) for 2-way banks
    const int vs0 = (tid >> 3) * 2;   // 0..62
    const int vh  = tid & 7;          // h = vh + 8i
    uint32_t vregs[8];
    const uint16_t* Vbu = (const uint16_t*)Vb;
#pragma unroll
    for (int i = 0; i < 8; i++) {
        uint32_t lo = Vbu[bbase + (size_t)vs0*64 + vh + 8*i];
        uint32_t hi = Vbu[bbase + (size_t)(vs0 + 1)*64 + vh + 8*i];
        vregs[i] = lo | (hi << 16);
    }
#pragma unroll
    for (int i = 0; i < 8; i++)
        *(uint32_t*)&Vt[0][(vh + 8*i)*VSTR + vs0] = vregs[i];
    __syncthreads();

    // S = Q K^T (K rows are B^T layout: lane n=l16 reads 8 contiguous k)
    f32x4 St[16];
#pragma unroll
    for (int i = 0; i < 16; i++) St[i] = (f32x4){0.f, 0.f, 0.f, 0.f};
#pragma unroll
    for (int nt = 0; nt < 16; nt++) if (nt < ntiles) {
        bf16x8 kf0 = *(const bf16x8*)&Ks[(nt*16 + l16)*KSTR + quad*8];
        bf16x8 kf1 = *(const bf16x8*)&Ks[(nt*16 + l16)*KSTR + 32 + quad*8];
        St[nt] = __builtin_amdgcn_mfma_f32_16x16x32_bf16(qf0, kf0, St[nt], 0, 0, 0);
        St[nt] = __builtin_amdgcn_mfma_f32_16x16x32_bf16(qf1, kf1, St[nt], 0, 0, 0);
    }

    // softmax in base-2 domain; C-layout rows = quad*4+r, col = l16
    const float sc2 = 0.125f * 1.44269504088896340736f;  // 1/sqrt(64) * log2(e)
    const int rowg0 = j*64 + wave*16 + quad*4;
    float mx[4], ls[4];
#pragma unroll
    for (int r = 0; r < 4; r++) mx[r] = -3.0e38f;
#pragma unroll
    for (int nt = 0; nt < 16; nt++) if (nt < ntiles) {
        const int cs = nt*16 + l16;
#pragma unroll
        for (int r = 0; r < 4; r++) {
            float s = (cs <= rowg0 + r) ? St[nt][r] * sc2 : -3.0e38f;
            St[nt][r] = s;
            mx[r] = fmaxf(mx[r], s);
        }
    }
#pragma unroll
    for (int d = 1; d < 16; d <<= 1)
#pragma unroll
        for (int r = 0; r < 4; r++)
            mx[r] = fmaxf(mx[r], __shfl_xor(mx[r], d, 64));
#pragma unroll
    for (int r = 0; r < 4; r++) ls[r] = 0.f;
#pragma unroll
    for (int nt = 0; nt < 16; nt++) if (nt < ntiles) {
#pragma unroll
        for (int r = 0; r < 4; r++) {
            float p = EXP2F(St[nt][r] - mx[r]);
            St[nt][r] = p;
            ls[r] += p;
        }
    }
#pragma unroll
    for (int d = 1; d < 16; d <<= 1)
#pragma unroll
        for (int r = 0; r < 4; r++)
            ls[r] += __shfl_xor(ls[r], d, 64);

    // O = P V, 64-s chunks double-buffered; P via per-wave LDS roundtrip
    f32x4 O[4];
#pragma unroll
    for (int i = 0; i < 4; i++) O[i] = (f32x4){0.f, 0.f, 0.f, 0.f};
    short* myP = Ps[wave];

#pragma unroll
    for (int c = 0; c < 4; c++) if (c < nchunks) {   // uniform guard: full unroll, static St indices
        const int buf = c & 1;
        if (c + 1 < nchunks) {
#pragma unroll
            for (int i = 0; i < 8; i++) {
                uint32_t lo = Vbu[bbase + (size_t)((c+1)*64 + vs0)*64 + vh + 8*i];
                uint32_t hi = Vbu[bbase + (size_t)((c+1)*64 + vs0 + 1)*64 + vh + 8*i];
                vregs[i] = lo | (hi << 16);
            }
        }
#pragma unroll
        for (int sub = 0; sub < 2; sub++) {
#pragma unroll
            for (int t2 = 0; t2 < 2; t2++) {
                const int nt = c*4 + sub*2 + t2;
#pragma unroll
                for (int r = 0; r < 4; r++)
                    myP[(quad*4 + r)*PSTR + t2*16 + l16] = f2bf(St[nt][r]);
            }
            bf16x8 pf = *(const bf16x8*)&myP[l16*PSTR + quad*8];  // wave-local: in-order LDS
#pragma unroll
            for (int ht = 0; ht < 4; ht++) {
                bf16x8 vf = *(const bf16x8*)&Vt[buf][(ht*16 + l16)*VSTR + sub*32 + quad*8];
                O[ht] = __builtin_amdgcn_mfma_f32_16x16x32_bf16(pf, vf, O[ht], 0, 0, 0);
            }
        }
        if (c + 1 < nchunks) {
#pragma unroll
            for (int i = 0; i < 8; i++)
                *(uint32_t*)&Vt[(c+1) & 1][(vh + 8*i)*VSTR + vs0] = vregs[i];
        }
        __syncthreads();
    }

    // epilogue: divide by row sums (same lane layout as O) and store fp32
    float rls[4];
#pragma unroll
    for (int r = 0; r < 4; r++) rls[r] = 1.0f / ls[r];
    const int orow0 = j*64 + wave*16 + quad*4;
#pragma unroll
    for (int ht = 0; ht < 4; ht++)
#pragma unroll
        for (int r = 0; r < 4; r++)
            out[((size_t)b*256 + orow0 + r)*64 + ht*16 + l16] = O[ht][r] * rls[r];
}

extern "C" void kernel_launch(void* const* d_in, const int* in_sizes, int n_in,
                              void* d_out, int out_size, void* d_ws, size_t ws_size,
                              hipStream_t stream) {
    const float* x  = (const float*)d_in[0];
    const float* Wk = (const float*)d_in[1];
    const float* bk = (const float*)d_in[2];
    const float* Wq = (const float*)d_in[3];
    const float* bq = (const float*)d_in[4];
    const float* Wv = (const float*)d_in[5];
    const float* bv = (const float*)d_in[6];
    float* out = (float*)d_out;

    char* ws = (char*)d_ws;
    short* Wt   = (short*)(ws);                          // 196608 B
    float* bcat = (float*)(ws + 196608);                 // 768 B
    short* Kb   = (short*)(ws + 262144);                 // 8 MB bf16 [65536][64]
    short* Qb   = (short*)(ws + 262144 + 8388608);       // 8 MB
    short* Vb   = (short*)(ws + 262144 + 16777216);      // 8 MB  (total ~24.3 MB of ws)

    prep_kernel<<<192, 256, 0, stream>>>(Wk, bk, Wq, bq, Wv, bv, Wt, bcat);
    qkv_kernel<<<512, 256, 0, stream>>>(x, Wt, bcat, Kb, Qb, Vb);
    attn_kernel<<<dim3(4, 256), 256, 0, stream>>>(Kb, Qb, Vb, out);
}

// Round 2
// 268.187 us; speedup vs baseline: 1.0064x; 1.0064x over previous
//
#include <hip/hip_runtime.h>
#include <stdint.h>

typedef __attribute__((ext_vector_type(8))) short bf16x8;
typedef __attribute__((ext_vector_type(4))) float f32x4;

#if __has_builtin(__builtin_amdgcn_exp2f)
#define EXP2F(x) __builtin_amdgcn_exp2f(x)
#else
#define EXP2F(x) exp2f(x)
#endif

__device__ __forceinline__ short f2bf(float f) {
    union { float f; uint32_t u; } c; c.f = f;
    return (short)((c.u + 0x7fffu + ((c.u >> 16) & 1u)) >> 16);
}

// ---- prep: Wt[192][512] bf16 (Wt[col][c] = W[c][col]; cols 0-63=K,64-127=Q,128-191=V), bcat[192] f32
__global__ void prep_kernel(const float* __restrict__ Wk, const float* __restrict__ bk,
                            const float* __restrict__ Wq, const float* __restrict__ bq,
                            const float* __restrict__ Wv, const float* __restrict__ bv,
                            short* __restrict__ Wt, float* __restrict__ bcat) {
    const int col = blockIdx.x;  // 0..191
    const float* W; const float* bb; int c0;
    if (col < 64)       { W = Wk; bb = bk; c0 = col; }
    else if (col < 128) { W = Wq; bb = bq; c0 = col - 64; }
    else                { W = Wv; bb = bv; c0 = col - 128; }
    for (int c = threadIdx.x; c < 512; c += blockDim.x)
        Wt[col * 512 + c] = f2bf(W[(size_t)c * 64 + c0]);
    if (threadIdx.x == 0) bcat[col] = bb[c0];
}

// ---- pass 1: fused QKV projection, barrier-free, LDS-free ----
// Each wave owns 32 rows x 192 cols. A-fragments loaded straight from global
// in MFMA A-layout (lane l16 -> row, quad*8 -> contiguous 8 k-elements, 32B),
// converted fp32->bf16 in-register. No __syncthreads anywhere: the 16-deep
// K-loop software-pipelines (manual 1-ahead prefetch) and 8 waves/CU of
// independent streams hide HBM/L3 latency.
__global__ __launch_bounds__(256, 2) void qkv_kernel(
    const float* __restrict__ x, const short* __restrict__ Wt,
    const float* __restrict__ bcat,
    short* __restrict__ Kb, short* __restrict__ Qb, short* __restrict__ Vb) {
    const int tid = threadIdx.x;
    const int wave = tid >> 6, lane = tid & 63;
    const int quad = lane >> 4, l16 = lane & 15;
    const int row0 = blockIdx.x * 128 + wave * 32;

    f32x4 acc[2][12];
#pragma unroll
    for (int m = 0; m < 2; m++)
#pragma unroll
        for (int i = 0; i < 12; i++) acc[m][i] = (f32x4){0.f, 0.f, 0.f, 0.f};

    // lane's A-stream base: row (row0 + l16 [+16]), k offset quad*8
    const float* xr0 = x + (size_t)(row0 + l16) * 512 + quad * 8;
    const float* xr1 = xr0 + (size_t)16 * 512;

    // prefetch c=0 (8 fp32 per row-stream = 2 float4 each)
    float4 p00 = ((const float4*)xr0)[0];
    float4 p01 = ((const float4*)xr0)[1];
    float4 p10 = ((const float4*)xr1)[0];
    float4 p11 = ((const float4*)xr1)[1];

    for (int c = 0; c < 16; c++) {
        // convert current chunk to A-fragments
        bf16x8 a0, a1;
        a0[0]=f2bf(p00.x); a0[1]=f2bf(p00.y); a0[2]=f2bf(p00.z); a0[3]=f2bf(p00.w);
        a0[4]=f2bf(p01.x); a0[5]=f2bf(p01.y); a0[6]=f2bf(p01.z); a0[7]=f2bf(p01.w);
        a1[0]=f2bf(p10.x); a1[1]=f2bf(p10.y); a1[2]=f2bf(p10.z); a1[3]=f2bf(p10.w);
        a1[4]=f2bf(p11.x); a1[5]=f2bf(p11.y); a1[6]=f2bf(p11.z); a1[7]=f2bf(p11.w);
        // prefetch next chunk (issues early; consumed next iteration)
        if (c < 15) {
            const float* n0 = xr0 + (c + 1) * 32;
            const float* n1 = xr1 + (c + 1) * 32;
            p00 = ((const float4*)n0)[0];
            p01 = ((const float4*)n0)[1];
            p10 = ((const float4*)n1)[0];
            p11 = ((const float4*)n1)[1];
        }
#pragma unroll
        for (int nt = 0; nt < 12; nt++) {
            bf16x8 bfrag = *(const bf16x8*)&Wt[(nt*16 + l16)*512 + c*32 + quad*8];
            acc[0][nt] = __builtin_amdgcn_mfma_f32_16x16x32_bf16(a0, bfrag, acc[0][nt], 0, 0, 0);
            acc[1][nt] = __builtin_amdgcn_mfma_f32_16x16x32_bf16(a1, bfrag, acc[1][nt], 0, 0, 0);
        }
    }

    // epilogue: C layout row=(lane>>4)*4+reg, col=lane&15 (m89/m91-verified)
#pragma unroll
    for (int m = 0; m < 2; m++) {
        const int rowbase = row0 + m*16 + quad*4;
#pragma unroll
        for (int nt = 0; nt < 12; nt++) {
            const int col = nt*16 + l16;
            const float bias = bcat[col];
            short* dst = (nt < 4) ? Kb : (nt < 8) ? Qb : Vb;
            const int h = col & 63;
#pragma unroll
            for (int r = 0; r < 4; r++)
                dst[(size_t)(rowbase + r)*64 + h] = f2bf(acc[m][nt][r] + bias);
        }
    }
}

// ---- pass 2: causal attention, block = (q-tile j, batch b) ----
#define KSTR 72   // K row stride (shorts): 2-way banks (free), 16B-aligned rows
#define VSTR 72   // Vt row stride within 64-s chunk
#define PSTR 40   // per-wave P scratch row stride

__global__ __launch_bounds__(256, 2) void attn_kernel(
    const short* __restrict__ Kb, const short* __restrict__ Qb,
    const short* __restrict__ Vb, float* __restrict__ out) {
    __shared__ __align__(16) short Ks[256 * KSTR];     // 36864 B
    __shared__ __align__(16) short Vt[2][64 * VSTR];   // 18432 B (double-buffered V^T chunks)
    __shared__ __align__(16) short Ps[4][16 * PSTR];   // 5120 B  (per-wave P C->A layout roundtrip)

    const int j = blockIdx.x;          // q tile 0..3 (rows 64j..64j+63)
    const int b = blockIdx.y;
    const int tid = threadIdx.x;
    const int wave = tid >> 6, lane = tid & 63;
    const int quad = lane >> 4, l16 = lane & 15;
    const int ntiles = 4 * (j + 1);    // 16-wide s tiles needed (causal)
    const int nchunks = j + 1;         // 64-wide s chunks
    const size_t bbase = (size_t)b * (256 * 64);

    // Q fragments: A layout lane m=l16, k=quad*8+jj (m120-verified)
    const int qrow = j*64 + wave*16 + l16;
    const bf16x8 qf0 = *(const bf16x8*)&Qb[bbase + (size_t)qrow*64 + quad*8];
    const bf16x8 qf1 = *(const bf16x8*)&Qb[bbase + (size_t)qrow*64 + 32 + quad*8];

    // stage K rows [0, 64*(j+1))
    {
        const int r = tid >> 2, seg = tid & 3;
        for (int rb = 0; rb < nchunks; rb++) {
            const int row = rb*64 + r;
            const uint4* src = (const uint4*)&Kb[bbase + (size_t)row*64 + seg*16];
            uint4 a0 = src[0], a1 = src[1];
            *(uint4*)&Ks[row*KSTR + seg*16]     = a0;
            *(uint4*)&Ks[row*KSTR + seg*16 + 8] = a1;
        }
    }
    // stage V chunk 0, transposed: Vt[h][s]; packed pair writes (s even) for 2-way banks
    const int vs0 = (tid >> 3) * 2;   // 0..62
    const int vh  = tid & 7;          // h = vh + 8i
    uint32_t vregs[8];
    const uint16_t* Vbu = (const uint16_t*)Vb;
#pragma unroll
    for (int i = 0; i < 8; i++) {
        uint32_t lo = Vbu[bbase + (size_t)vs0*64 + vh + 8*i];
        uint32_t hi = Vbu[bbase + (size_t)(vs0 + 1)*64 + vh + 8*i];
        vregs[i] = lo | (hi << 16);
    }
#pragma unroll
    for (int i = 0; i < 8; i++)
        *(uint32_t*)&Vt[0][(vh + 8*i)*VSTR + vs0] = vregs[i];
    __syncthreads();

    // S = Q K^T (K rows are B^T layout: lane n=l16 reads 8 contiguous k)
    f32x4 St[16];
#pragma unroll
    for (int i = 0; i < 16; i++) St[i] = (f32x4){0.f, 0.f, 0.f, 0.f};
#pragma unroll
    for (int nt = 0; nt < 16; nt++) if (nt < ntiles) {
        bf16x8 kf0 = *(const bf16x8*)&Ks[(nt*16 + l16)*KSTR + quad*8];
        bf16x8 kf1 = *(const bf16x8*)&Ks[(nt*16 + l16)*KSTR + 32 + quad*8];
        St[nt] = __builtin_amdgcn_mfma_f32_16x16x32_bf16(qf0, kf0, St[nt], 0, 0, 0);
        St[nt] = __builtin_amdgcn_mfma_f32_16x16x32_bf16(qf1, kf1, St[nt], 0, 0, 0);
    }

    // softmax in base-2 domain; C-layout rows = quad*4+r, col = l16
    const float sc2 = 0.125f * 1.44269504088896340736f;  // 1/sqrt(64) * log2(e)
    const int rowg0 = j*64 + wave*16 + quad*4;
    float mx[4], ls[4];
#pragma unroll
    for (int r = 0; r < 4; r++) mx[r] = -3.0e38f;
#pragma unroll
    for (int nt = 0; nt < 16; nt++) if (nt < ntiles) {
        const int cs = nt*16 + l16;
#pragma unroll
        for (int r = 0; r < 4; r++) {
            float s = (cs <= rowg0 + r) ? St[nt][r] * sc2 : -3.0e38f;
            St[nt][r] = s;
            mx[r] = fmaxf(mx[r], s);
        }
    }
#pragma unroll
    for (int d = 1; d < 16; d <<= 1)
#pragma unroll
        for (int r = 0; r < 4; r++)
            mx[r] = fmaxf(mx[r], __shfl_xor(mx[r], d, 64));
#pragma unroll
    for (int r = 0; r < 4; r++) ls[r] = 0.f;
#pragma unroll
    for (int nt = 0; nt < 16; nt++) if (nt < ntiles) {
#pragma unroll
        for (int r = 0; r < 4; r++) {
            float p = EXP2F(St[nt][r] - mx[r]);
            St[nt][r] = p;
            ls[r] += p;
        }
    }
#pragma unroll
    for (int d = 1; d < 16; d <<= 1)
#pragma unroll
        for (int r = 0; r < 4; r++)
            ls[r] += __shfl_xor(ls[r], d, 64);

    // O = P V, 64-s chunks double-buffered; P via per-wave LDS roundtrip
    f32x4 O[4];
#pragma unroll
    for (int i = 0; i < 4; i++) O[i] = (f32x4){0.f, 0.f, 0.f, 0.f};
    short* myP = Ps[wave];

#pragma unroll
    for (int c = 0; c < 4; c++) if (c < nchunks) {   // uniform guard: full unroll, static St indices
        const int buf = c & 1;
        if (c + 1 < nchunks) {
#pragma unroll
            for (int i = 0; i < 8; i++) {
                uint32_t lo = Vbu[bbase + (size_t)((c+1)*64 + vs0)*64 + vh + 8*i];
                uint32_t hi = Vbu[bbase + (size_t)((c+1)*64 + vs0 + 1)*64 + vh + 8*i];
                vregs[i] = lo | (hi << 16);
            }
        }
#pragma unroll
        for (int sub = 0; sub < 2; sub++) {
#pragma unroll
            for (int t2 = 0; t2 < 2; t2++) {
                const int nt = c*4 + sub*2 + t2;
#pragma unroll
                for (int r = 0; r < 4; r++)
                    myP[(quad*4 + r)*PSTR + t2*16 + l16] = f2bf(St[nt][r]);
            }
            bf16x8 pf = *(const bf16x8*)&myP[l16*PSTR + quad*8];  // wave-local: in-order LDS
#pragma unroll
            for (int ht = 0; ht < 4; ht++) {
                bf16x8 vf = *(const bf16x8*)&Vt[buf][(ht*16 + l16)*VSTR + sub*32 + quad*8];
                O[ht] = __builtin_amdgcn_mfma_f32_16x16x32_bf16(pf, vf, O[ht], 0, 0, 0);
            }
        }
        if (c + 1 < nchunks) {
#pragma unroll
            for (int i = 0; i < 8; i++)
                *(uint32_t*)&Vt[(c+1) & 1][(vh + 8*i)*VSTR + vs0] = vregs[i];
        }
        __syncthreads();
    }

    // epilogue: divide by row sums (same lane layout as O) and store fp32
    float rls[4];
#pragma unroll
    for (int r = 0; r < 4; r++) rls[r] = 1.0f / ls[r];
    const int orow0 = j*64 + wave*16 + quad*4;
#pragma unroll
    for (int ht = 0; ht < 4; ht++)
#pragma unroll
        for (int r = 0; r < 4; r++)
            out[((size_t)b*256 + orow0 + r)*64 + ht*16 + l16] = O[ht][r] * rls[r];
}

extern "C" void kernel_launch(void* const* d_in, const int* in_sizes, int n_in,
                              void* d_out, int out_size, void* d_ws, size_t ws_size,
                              hipStream_t stream) {
    const float* x  = (const float*)d_in[0];
    const float* Wk = (const float*)d_in[1];
    const float* bk = (const float*)d_in[2];
    const float* Wq = (const float*)d_in[3];
    const float* bq = (const float*)d_in[4];
    const float* Wv = (const float*)d_in[5];
    const float* bv = (const float*)d_in[6];
    float* out = (float*)d_out;

    char* ws = (char*)d_ws;
    short* Wt   = (short*)(ws);                          // 196608 B
    float* bcat = (float*)(ws + 196608);                 // 768 B
    short* Kb   = (short*)(ws + 262144);                 // 8 MB bf16 [65536][64]
    short* Qb   = (short*)(ws + 262144 + 8388608);       // 8 MB
    short* Vb   = (short*)(ws + 262144 + 16777216);      // 8 MB  (total ~24.3 MB of ws)

    prep_kernel<<<192, 256, 0, stream>>>(Wk, bk, Wq, bq, Wv, bv, Wt, bcat);
    qkv_kernel<<<512, 256, 0, stream>>>(x, Wt, bcat, Kb, Qb, Vb);
    attn_kernel<<<dim3(4, 256), 256, 0, stream>>>(Kb, Qb, Vb, out);
}

// Round 5
// 233.216 us; speedup vs baseline: 1.1573x; 1.1499x over previous
//
#include <hip/hip_runtime.h>
#include <stdint.h>

typedef __attribute__((ext_vector_type(8))) short bf16x8;
typedef __attribute__((ext_vector_type(4))) float f32x4;

#if __has_builtin(__builtin_amdgcn_exp2f)
#define EXP2F(x) __builtin_amdgcn_exp2f(x)
#else
#define EXP2F(x) exp2f(x)
#endif

__device__ __forceinline__ short f2bf(float f) {
    union { float f; uint32_t u; } c; c.f = f;
    return (short)((c.u + 0x7fffu + ((c.u >> 16) & 1u)) >> 16);
}

// async global->LDS 16B/lane: dest = wave-uniform base + lane*16 (m97/m104 semantics)
typedef __attribute__((address_space(1))) void gvoid;
typedef __attribute__((address_space(3))) void lvoid;
__device__ __forceinline__ void async_cp16(const void* g, void* l) {
    __builtin_amdgcn_global_load_lds((gvoid*)g, (lvoid*)l, 16, 0, 0);
}

// ---- prep: Wt2g chunk-major [16 kchunks][192 cols][32 k] bf16 + bcat[192] f32
__global__ void prep_kernel(const float* __restrict__ Wk, const float* __restrict__ bk,
                            const float* __restrict__ Wq, const float* __restrict__ bq,
                            const float* __restrict__ Wv, const float* __restrict__ bv,
                            short* __restrict__ Wt2g, float* __restrict__ bcat) {
    const int col = blockIdx.x;  // 0..191 (0-63=K, 64-127=Q, 128-191=V)
    const float* W; const float* bb; int c0;
    if (col < 64)       { W = Wk; bb = bk; c0 = col; }
    else if (col < 128) { W = Wq; bb = bq; c0 = col - 64; }
    else                { W = Wv; bb = bv; c0 = col - 128; }
    for (int c = threadIdx.x; c < 512; c += blockDim.x)
        Wt2g[(c >> 5) * (192 * 32) + col * 32 + (c & 31)] = f2bf(W[(size_t)c * 64 + c0]);
    if (threadIdx.x == 0) bcat[col] = bb[c0];
}

// ---- pass 1: fused QKV projection, m97-style global_load_lds staging ----
// tile 128 rows x 192 cols, BK=32 fp32, double-buffered LDS; epilogue through
// LDS for coalesced dwordx4 stores; V written TRANSPOSED (Vt[b][h][s]).
__global__ __launch_bounds__(256, 2) void qkv_kernel(
    const float* __restrict__ x, const short* __restrict__ Wt2g,
    const float* __restrict__ bcat,
    short* __restrict__ Kb, short* __restrict__ Qb, short* __restrict__ Vt) {
    __shared__ __align__(16) char smem[57344];
#define XS(bufp)  ((float*)(smem + (bufp) * 16384))            // [128 rows][32 f32], slot-swizzled
#define WSB(bufp) ((short*)(smem + 32768 + (bufp) * 12288))    // [192 cols][32 bf16], slot-swizzled
    short* ce = (short*)smem;                                  // epilogue [128][CEP]
    const int CEP = 216;  // shorts; 432 B rows: 16B-aligned, breaks pow2 banks

    const int tid = threadIdx.x;
    const int wave = tid >> 6, lane = tid & 63;
    const int quad = lane >> 4, l16 = lane & 15;
    const int row0 = blockIdx.x * 128;

    f32x4 acc[2][12];
#pragma unroll
    for (int m = 0; m < 2; m++)
#pragma unroll
        for (int i = 0; i < 12; i++) acc[m][i] = (f32x4){0.f, 0.f, 0.f, 0.f};

    // --- staging (per-chunk) ---
    // x chunk: 128 rows x 128B -> 16 wave-instrs (4/wave). LDS slot s' holds src slot s'^((r&3)<<1)
    const int xr = (lane >> 3);            // row-within-8
    const int xsl = lane & 7;              // dest slot
    // Wt chunk: 192 cols x 64B -> 12 wave-instrs (3/wave). slot s' holds src slot s'^(col&3)
    const int wc = lane >> 2;              // col-within-16
    const int wsl = lane & 3;

#define STAGE_X(cc, bufp)                                                          \
    for (int q = 0; q < 4; q++) {                                                  \
        const int i = wave * 4 + q;                                                \
        const int r = i * 8 + xr;                                                  \
        const int s = xsl ^ ((r & 3) << 1);                                        \
        async_cp16(x + (size_t)(row0 + r) * 512 + (cc) * 32 + s * 4,               \
                   smem + (bufp) * 16384 + i * 1024);                              \
    }
#define STAGE_W(cc, bufp)                                                          \
    for (int q = 0; q < 3; q++) {                                                  \
        const int i = wave * 3 + q;                                                \
        const int col = i * 16 + wc;                                               \
        const int s = wsl ^ (col & 3);                                             \
        async_cp16(Wt2g + ((size_t)(cc) * 192 + col) * 32 + s * 8,                 \
                   smem + 32768 + (bufp) * 12288 + i * 1024);                      \
    }

    STAGE_X(0, 0)
    STAGE_W(0, 0)
    __syncthreads();

    const int axoff = (quad ^ (l16 & 3)) * 8;   // A slot-pair (32B) after swizzle
    for (int c = 0; c < 16; c++) {
        const int buf = c & 1;
        if (c < 15) { STAGE_X(c + 1, buf ^ 1) STAGE_W(c + 1, buf ^ 1) }
        // A-frags from LDS fp32, convert in-reg.  ROWS ARE wave*32 + l16 (+16)!
        const float* pa0 = XS(buf) + (wave * 32 + l16) * 32 + axoff;
        const float* pa1 = XS(buf) + (wave * 32 + 16 + l16) * 32 + axoff;
        f32x4 u0 = *(const f32x4*)pa0, u1 = *(const f32x4*)(pa0 + 4);
        f32x4 u2 = *(const f32x4*)pa1, u3 = *(const f32x4*)(pa1 + 4);
        bf16x8 a0, a1;
#pragma unroll
        for (int i = 0; i < 4; i++) { a0[i] = f2bf(u0[i]); a0[4+i] = f2bf(u1[i]); }
#pragma unroll
        for (int i = 0; i < 4; i++) { a1[i] = f2bf(u2[i]); a1[4+i] = f2bf(u3[i]); }
        const short* wb = WSB(buf);
#pragma unroll
        for (int nt = 0; nt < 12; nt++) {
            bf16x8 bfrag = *(const bf16x8*)&wb[(nt * 16 + l16) * 32 + axoff];
            acc[0][nt] = __builtin_amdgcn_mfma_f32_16x16x32_bf16(a0, bfrag, acc[0][nt], 0, 0, 0);
            acc[1][nt] = __builtin_amdgcn_mfma_f32_16x16x32_bf16(a1, bfrag, acc[1][nt], 0, 0, 0);
        }
        __syncthreads();
    }

    // --- epilogue: C frags -> ce LDS (bf16, +bias), then coalesced readout ---
#pragma unroll
    for (int m = 0; m < 2; m++) {
        const int lrow = wave * 32 + m * 16 + quad * 4;
#pragma unroll
        for (int nt = 0; nt < 12; nt++) {
            const int col = nt * 16 + l16;
            const float bias = bcat[col];
#pragma unroll
            for (int r = 0; r < 4; r++)
                ce[(lrow + r) * CEP + col] = f2bf(acc[m][nt][r] + bias);
        }
    }
    __syncthreads();

    // K/Q readout: 2 threads/row, 64B halves, dwordx4 in+out (fully coalesced)
    {
        const int row = tid >> 1, half = tid & 1;
        const size_t gro = (size_t)(row0 + row) * 64 + half * 32;
#pragma unroll
        for (int j4 = 0; j4 < 4; j4++) {
            uint4 kv = *(const uint4*)&ce[row * CEP + half * 32 + j4 * 8];
            *(uint4*)&Kb[gro + j4 * 8] = kv;
            uint4 qv = *(const uint4*)&ce[row * CEP + 64 + half * 32 + j4 * 8];
            *(uint4*)&Qb[gro + j4 * 8] = qv;
        }
    }
    // V transposed readout -> Vt[b][h][s]  (b = row0>>8, s0 = row0&255)
    {
        const int h = tid >> 2, sq = tid & 3;
        const size_t vbase = (size_t)(row0 >> 8) * 16384 + (size_t)h * 256 + (row0 & 255) + sq * 32;
        const uint16_t* ceu = (const uint16_t*)ce;
#pragma unroll
        for (int g = 0; g < 4; g++) {
            uint4 v;
            uint32_t* vw = (uint32_t*)&v;
#pragma unroll
            for (int p = 0; p < 4; p++) {
                const int sl = sq * 32 + g * 8 + p * 2;
                uint32_t lo = ceu[sl * CEP + 128 + h];
                uint32_t hi = ceu[(sl + 1) * CEP + 128 + h];
                vw[p] = lo | (hi << 16);
            }
            *(uint4*)&Vt[vbase + g * 8] = v;
        }
    }
#undef XS
#undef WSB
#undef STAGE_X
#undef STAGE_W
}

// ---- pass 2: causal attention; K/Vt staged via global_load_lds, swizzled ----
#define PSTR 40   // per-wave P scratch row stride (shorts); 80B rows (16B-aligned)

__global__ __launch_bounds__(256, 2) void attn_kernel(
    const short* __restrict__ Kb, const short* __restrict__ Qb,
    const short* __restrict__ Vt, float* __restrict__ out) {
    __shared__ __align__(16) short Ks[256 * 64];      // 32768 B, rows 128B, slot^(row&7) swizzle
    __shared__ __align__(16) short Vts[2][64 * 64];   // 16384 B, rows 128B, slot^(h&7) swizzle
    __shared__ __align__(16) short Ps[4][16 * PSTR];  // 5120 B, per-wave P C->A roundtrip

    const int j = 3 - blockIdx.x;      // heavy q-tiles first
    const int b = blockIdx.y;
    const int tid = threadIdx.x;
    const int wave = tid >> 6, lane = tid & 63;
    const int quad = lane >> 4, l16 = lane & 15;
    const int ntiles = 4 * (j + 1);
    const int nchunks = j + 1;
    const size_t bbase = (size_t)b * (256 * 64);

    const int sr = lane >> 3;          // staging: row-within-8
    const int ssl = lane & 7;          // staging: dest slot
    const int ssrc = (ssl ^ sr) * 8;   // src slot offset (shorts); (row&7)==sr for i*8 rows

    // stage K rows [0, 64*(j+1)): 8*(j+1) wave-instrs, round-robin over waves
    for (int q = 0; q < 2 * nchunks; q++) {
        const int i = q * 4 + wave;    // 0..8*nchunks-1
        const int row = i * 8 + sr;
        async_cp16(Kb + bbase + (size_t)row * 64 + ssrc, (char*)Ks + i * 1024);
    }
    // stage Vt chunk 0: rows h, window [0,64) s
#define STAGE_V(cc, bufp)                                                          \
    for (int q = 0; q < 2; q++) {                                                  \
        const int i = q * 4 + wave;                                                \
        const int h = i * 8 + sr;                                                  \
        async_cp16(Vt + (size_t)b * 16384 + (size_t)h * 256 + (cc) * 64 + ssrc,    \
                   (char*)Vts[bufp] + i * 1024);                                   \
    }
    STAGE_V(0, 0)

    // Q frags (A layout) direct from global — small, once
    const int qrow = j * 64 + wave * 16 + l16;
    const bf16x8 qf0 = *(const bf16x8*)&Qb[bbase + (size_t)qrow * 64 + quad * 8];
    const bf16x8 qf1 = *(const bf16x8*)&Qb[bbase + (size_t)qrow * 64 + 32 + quad * 8];
    __syncthreads();

    // S = Q K^T from swizzled Ks: kf0 slot=quad, kf1 slot=quad+4, ^ (l16&7)
    f32x4 St[16];
#pragma unroll
    for (int i = 0; i < 16; i++) St[i] = (f32x4){0.f, 0.f, 0.f, 0.f};
#pragma unroll
    for (int nt = 0; nt < 16; nt++) if (nt < ntiles) {
        const short* kr = &Ks[(nt * 16 + l16) * 64];
        bf16x8 kf0 = *(const bf16x8*)&kr[(quad ^ (l16 & 7)) * 8];
        bf16x8 kf1 = *(const bf16x8*)&kr[((quad + 4) ^ (l16 & 7)) * 8];
        St[nt] = __builtin_amdgcn_mfma_f32_16x16x32_bf16(qf0, kf0, St[nt], 0, 0, 0);
        St[nt] = __builtin_amdgcn_mfma_f32_16x16x32_bf16(qf1, kf1, St[nt], 0, 0, 0);
    }

    // softmax (base-2); C-layout rows = quad*4+r, col = l16
    const float sc2 = 0.125f * 1.44269504088896340736f;
    const int rowg0 = j * 64 + wave * 16 + quad * 4;
    float mx[4], ls[4];
#pragma unroll
    for (int r = 0; r < 4; r++) mx[r] = -3.0e38f;
#pragma unroll
    for (int nt = 0; nt < 16; nt++) if (nt < ntiles) {
        const int cs = nt * 16 + l16;
#pragma unroll
        for (int r = 0; r < 4; r++) {
            float s = (cs <= rowg0 + r) ? St[nt][r] * sc2 : -3.0e38f;
            St[nt][r] = s;
            mx[r] = fmaxf(mx[r], s);
        }
    }
#pragma unroll
    for (int d = 1; d < 16; d <<= 1)
#pragma unroll
        for (int r = 0; r < 4; r++)
            mx[r] = fmaxf(mx[r], __shfl_xor(mx[r], d, 64));
#pragma unroll
    for (int r = 0; r < 4; r++) ls[r] = 0.f;
#pragma unroll
    for (int nt = 0; nt < 16; nt++) if (nt < ntiles) {
#pragma unroll
        for (int r = 0; r < 4; r++) {
            float p = EXP2F(St[nt][r] - mx[r]);
            St[nt][r] = p;
            ls[r] += p;
        }
    }
#pragma unroll
    for (int d = 1; d < 16; d <<= 1)
#pragma unroll
        for (int r = 0; r < 4; r++)
            ls[r] += __shfl_xor(ls[r], d, 64);

    // O = P V over 64-s chunks, double-buffered Vts; P via wave-local LDS roundtrip
    f32x4 O[4];
#pragma unroll
    for (int i = 0; i < 4; i++) O[i] = (f32x4){0.f, 0.f, 0.f, 0.f};
    short* myP = Ps[wave];

#pragma unroll
    for (int c = 0; c < 4; c++) if (c < nchunks) {
        const int buf = c & 1;
        if (c + 1 < nchunks) { STAGE_V(c + 1, buf ^ 1) }
#pragma unroll
        for (int sub = 0; sub < 2; sub++) {
#pragma unroll
            for (int t2 = 0; t2 < 2; t2++) {
                const int nt = c * 4 + sub * 2 + t2;
#pragma unroll
                for (int r = 0; r < 4; r++)
                    myP[(quad * 4 + r) * PSTR + t2 * 16 + l16] = f2bf(St[nt][r]);
            }
            bf16x8 pf = *(const bf16x8*)&myP[l16 * PSTR + quad * 8];
#pragma unroll
            for (int ht = 0; ht < 4; ht++) {
                bf16x8 vf = *(const bf16x8*)&Vts[buf][(ht * 16 + l16) * 64 +
                                                      (((sub * 4 + quad) ^ (l16 & 7)) * 8)];
                O[ht] = __builtin_amdgcn_mfma_f32_16x16x32_bf16(pf, vf, O[ht], 0, 0, 0);
            }
        }
        __syncthreads();
    }

    float rls[4];
#pragma unroll
    for (int r = 0; r < 4; r++) rls[r] = 1.0f / ls[r];
    const int orow0 = j * 64 + wave * 16 + quad * 4;
#pragma unroll
    for (int ht = 0; ht < 4; ht++)
#pragma unroll
        for (int r = 0; r < 4; r++)
            out[((size_t)b * 256 + orow0 + r) * 64 + ht * 16 + l16] = O[ht][r] * rls[r];
}

extern "C" void kernel_launch(void* const* d_in, const int* in_sizes, int n_in,
                              void* d_out, int out_size, void* d_ws, size_t ws_size,
                              hipStream_t stream) {
    const float* x  = (const float*)d_in[0];
    const float* Wk = (const float*)d_in[1];
    const float* bk = (const float*)d_in[2];
    const float* Wq = (const float*)d_in[3];
    const float* bq = (const float*)d_in[4];
    const float* Wv = (const float*)d_in[5];
    const float* bv = (const float*)d_in[6];
    float* out = (float*)d_out;

    char* ws = (char*)d_ws;
    short* Wt2g = (short*)(ws);                          // 196608 B (chunk-major)
    float* bcat = (float*)(ws + 196608);                 // 768 B
    short* Kb   = (short*)(ws + 262144);                 // 8 MB bf16 [65536][64]
    short* Qb   = (short*)(ws + 262144 + 8388608);       // 8 MB
    short* Vt   = (short*)(ws + 262144 + 16777216);      // 8 MB bf16 [256 b][64 h][256 s]

    prep_kernel<<<192, 256, 0, stream>>>(Wk, bk, Wq, bq, Wv, bv, Wt2g, bcat);
    qkv_kernel<<<512, 256, 0, stream>>>(x, Wt2g, bcat, Kb, Qb, Vt);
    attn_kernel<<<dim3(4, 256), 256, 0, stream>>>(Kb, Qb, Vt, out);
}

// Round 6
// 229.594 us; speedup vs baseline: 1.1755x; 1.0158x over previous
//
#include <hip/hip_runtime.h>
#include <stdint.h>

typedef __attribute__((ext_vector_type(8))) short bf16x8;
typedef __attribute__((ext_vector_type(4))) float f32x4;

#if __has_builtin(__builtin_amdgcn_exp2f)
#define EXP2F(x) __builtin_amdgcn_exp2f(x)
#else
#define EXP2F(x) exp2f(x)
#endif

__device__ __forceinline__ short f2bf(float f) {
    union { float f; uint32_t u; } c; c.f = f;
    return (short)((c.u + 0x7fffu + ((c.u >> 16) & 1u)) >> 16);
}

// ---- prep: Wt2g chunk-major [16 kchunks][192 cols][32 k] bf16 + bcat[192] f32
__global__ void prep_kernel(const float* __restrict__ Wk, const float* __restrict__ bk,
                            const float* __restrict__ Wq, const float* __restrict__ bq,
                            const float* __restrict__ Wv, const float* __restrict__ bv,
                            short* __restrict__ Wt2g, float* __restrict__ bcat) {
    const int col = blockIdx.x;  // 0..191 (0-63=K, 64-127=Q, 128-191=V)
    const float* W; const float* bb; int c0;
    if (col < 64)       { W = Wk; bb = bk; c0 = col; }
    else if (col < 128) { W = Wq; bb = bq; c0 = col - 64; }
    else                { W = Wv; bb = bv; c0 = col - 128; }
    for (int c = threadIdx.x; c < 512; c += blockDim.x)
        Wt2g[(c >> 5) * (192 * 32) + col * 32 + (c & 31)] = f2bf(W[(size_t)c * 64 + c0]);
    if (threadIdx.x == 0) bcat[col] = bb[c0];
}

// ---- fused per-batch kernel: QKV-GEMM (barrier-free) -> LDS -> causal attention ----
// Block = 1 batch (256 rows), 512 threads = 8 waves. Wave w owns m-tiles {w, 15-w}
// in BOTH phases (balanced causal work: (w+1)+(16-w)=17 tiles const).
// LDS (dynamic, 108544 B): Ks[256][64] / Qs[256][64] rows swizzled slot^=(row&7);
// Vts[64 h][256 s] swizzled slot^=(h&7); Ps = per-wave 16x40 P-roundtrip scratch.
#define PSTR 40

__global__ __launch_bounds__(512, 2) void fused_kernel(
    const float* __restrict__ x, const short* __restrict__ Wt2g,
    const float* __restrict__ bcat, float* __restrict__ out) {
    extern __shared__ __align__(16) char smem[];
    short* Ks  = (short*)smem;              // 32768 B
    short* Qs  = (short*)(smem + 32768);    // 32768 B
    short* Vts = (short*)(smem + 65536);    // 32768 B
    short* Ps  = (short*)(smem + 98304);    // 10240 B

    const int tid = threadIdx.x;
    const int wave = tid >> 6, lane = tid & 63;
    const int quad = lane >> 4, l16 = lane & 15;
    const int b = blockIdx.x;
    const int ta = wave, tb = 15 - wave;

    // ================= phase 1: QKV projection =================
    f32x4 acc[2][12];
#pragma unroll
    for (int m = 0; m < 2; m++)
#pragma unroll
        for (int i = 0; i < 12; i++) acc[m][i] = (f32x4){0.f, 0.f, 0.f, 0.f};

    const float* xA0 = x + ((size_t)b * 256 + ta * 16 + l16) * 512 + quad * 8;
    const float* xA1 = x + ((size_t)b * 256 + tb * 16 + l16) * 512 + quad * 8;

    // manual 1-deep A prefetch; no barriers anywhere in this loop
    f32x4 p00 = *(const f32x4*)xA0, p01 = *(const f32x4*)(xA0 + 4);
    f32x4 p10 = *(const f32x4*)xA1, p11 = *(const f32x4*)(xA1 + 4);

    for (int kc = 0; kc < 16; kc++) {
        bf16x8 a0, a1;
#pragma unroll
        for (int i = 0; i < 4; i++) { a0[i] = f2bf(p00[i]); a0[4 + i] = f2bf(p01[i]); }
#pragma unroll
        for (int i = 0; i < 4; i++) { a1[i] = f2bf(p10[i]); a1[4 + i] = f2bf(p11[i]); }
        if (kc < 15) {
            p00 = *(const f32x4*)(xA0 + (kc + 1) * 32);
            p01 = *(const f32x4*)(xA0 + (kc + 1) * 32 + 4);
            p10 = *(const f32x4*)(xA1 + (kc + 1) * 32);
            p11 = *(const f32x4*)(xA1 + (kc + 1) * 32 + 4);
        }
        const short* wkc = Wt2g + kc * 6144 + l16 * 32 + quad * 8;  // B-frag: L2-hot
#pragma unroll
        for (int nt = 0; nt < 12; nt++) {
            bf16x8 bfrag = *(const bf16x8*)(wkc + nt * 512);
            acc[0][nt] = __builtin_amdgcn_mfma_f32_16x16x32_bf16(a0, bfrag, acc[0][nt], 0, 0, 0);
            acc[1][nt] = __builtin_amdgcn_mfma_f32_16x16x32_bf16(a1, bfrag, acc[1][nt], 0, 0, 0);
        }
    }

    // ---- epilogue: C-layout (row=quad*4+r, col=l16) -> swizzled LDS, +bias ----
#pragma unroll
    for (int m = 0; m < 2; m++) {
        const int t = m ? tb : ta;
#pragma unroll
        for (int nt = 0; nt < 12; nt++) {
            const int col = nt * 16 + l16;
            const float bias = bcat[col];
            const int h = col & 63;
#pragma unroll
            for (int r = 0; r < 4; r++) {
                const short v = f2bf(acc[m][nt][r] + bias);
                const int row = t * 16 + quad * 4 + r;
                if (nt < 4)
                    Ks[row * 64 + (((h >> 3) ^ (row & 7)) << 3) + (h & 7)] = v;
                else if (nt < 8)
                    Qs[row * 64 + (((h >> 3) ^ (row & 7)) << 3) + (h & 7)] = v;
                else
                    Vts[h * 256 + (((row >> 3) ^ (h & 7)) << 3) + (row & 7)] = v;
            }
        }
    }
    __syncthreads();   // the ONLY block-wide barrier

    // ================= phase 2: causal attention, all-LDS =================
    const float sc2 = 0.125f * 1.44269504088896340736f;  // 1/sqrt(64) * log2(e)
    short* myP = Ps + wave * (16 * PSTR);

#pragma unroll
    for (int ti = 0; ti < 2; ti++) {
        const int t = ti ? tb : ta;          // q-tile (rows t*16..t*16+15); wave-uniform
        // Q A-frags from swizzled Qs
        const int qrow = t * 16 + l16;
        const int sw = l16 & 7;
        bf16x8 qf0 = *(const bf16x8*)&Qs[qrow * 64 + ((quad ^ sw) << 3)];
        bf16x8 qf1 = *(const bf16x8*)&Qs[qrow * 64 + (((4 + quad) ^ sw) << 3)];

        f32x4 St[16];
#pragma unroll
        for (int i = 0; i < 16; i++) St[i] = (f32x4){0.f, 0.f, 0.f, 0.f};
#pragma unroll
        for (int nt = 0; nt < 16; nt++) if (nt <= t) {
            const int krow = nt * 16 + l16;
            bf16x8 kf0 = *(const bf16x8*)&Ks[krow * 64 + ((quad ^ sw) << 3)];
            bf16x8 kf1 = *(const bf16x8*)&Ks[krow * 64 + (((4 + quad) ^ sw) << 3)];
            St[nt] = __builtin_amdgcn_mfma_f32_16x16x32_bf16(qf0, kf0, St[nt], 0, 0, 0);
            St[nt] = __builtin_amdgcn_mfma_f32_16x16x32_bf16(qf1, kf1, St[nt], 0, 0, 0);
        }

        // mask + base-2 softmax; C-layout rows = quad*4+r, col = l16
        const int rowq = t * 16 + quad * 4;
        float mx[4], ls[4];
#pragma unroll
        for (int r = 0; r < 4; r++) mx[r] = -3.0e38f;
#pragma unroll
        for (int nt = 0; nt < 16; nt++) if (nt <= t) {
            const int cs = nt * 16 + l16;
#pragma unroll
            for (int r = 0; r < 4; r++) {
                float s = (cs <= rowq + r) ? St[nt][r] * sc2 : -3.0e38f;
                St[nt][r] = s;
                mx[r] = fmaxf(mx[r], s);
            }
        }
#pragma unroll
        for (int d = 1; d < 16; d <<= 1)
#pragma unroll
            for (int r = 0; r < 4; r++)
                mx[r] = fmaxf(mx[r], __shfl_xor(mx[r], d, 64));
#pragma unroll
        for (int r = 0; r < 4; r++) ls[r] = 0.f;
#pragma unroll
        for (int nt = 0; nt < 16; nt++) if (nt <= t) {
#pragma unroll
            for (int r = 0; r < 4; r++) {
                float p = EXP2F(St[nt][r] - mx[r]);
                St[nt][r] = p;                 // St[nt>t] stays 0 == correct P
                ls[r] += p;
            }
        }
#pragma unroll
        for (int d = 1; d < 16; d <<= 1)
#pragma unroll
            for (int r = 0; r < 4; r++)
                ls[r] += __shfl_xor(ls[r], d, 64);

        // O = P V over 32-s chunks; P via wave-local LDS C->A roundtrip
        f32x4 O[4];
#pragma unroll
        for (int i = 0; i < 4; i++) O[i] = (f32x4){0.f, 0.f, 0.f, 0.f};
        const int nch = (t + 2) >> 1;        // ceil((t+1)/2), wave-uniform
#pragma unroll
        for (int c2 = 0; c2 < 8; c2++) if (c2 < nch) {
#pragma unroll
            for (int t2i = 0; t2i < 2; t2i++) {
                const int nt = c2 * 2 + t2i; // St[nt]=0 beyond diagonal => P=0
#pragma unroll
                for (int r = 0; r < 4; r++)
                    myP[(quad * 4 + r) * PSTR + t2i * 16 + l16] = f2bf(St[nt][r]);
            }
            bf16x8 pf = *(const bf16x8*)&myP[l16 * PSTR + quad * 8];
#pragma unroll
            for (int ht = 0; ht < 4; ht++) {
                const int h = ht * 16 + l16;
                bf16x8 vf = *(const bf16x8*)&Vts[h * 256 + ((((c2 * 4 + quad)) ^ (h & 7)) << 3)];
                O[ht] = __builtin_amdgcn_mfma_f32_16x16x32_bf16(pf, vf, O[ht], 0, 0, 0);
            }
        }

        float rls[4];
#pragma unroll
        for (int r = 0; r < 4; r++) rls[r] = 1.0f / ls[r];
#pragma unroll
        for (int ht = 0; ht < 4; ht++)
#pragma unroll
            for (int r = 0; r < 4; r++)
                out[((size_t)b * 256 + rowq + r) * 64 + ht * 16 + l16] = O[ht][r] * rls[r];
    }
}

extern "C" void kernel_launch(void* const* d_in, const int* in_sizes, int n_in,
                              void* d_out, int out_size, void* d_ws, size_t ws_size,
                              hipStream_t stream) {
    const float* x  = (const float*)d_in[0];
    const float* Wk = (const float*)d_in[1];
    const float* bk = (const float*)d_in[2];
    const float* Wq = (const float*)d_in[3];
    const float* bq = (const float*)d_in[4];
    const float* Wv = (const float*)d_in[5];
    const float* bv = (const float*)d_in[6];
    float* out = (float*)d_out;

    char* ws = (char*)d_ws;
    short* Wt2g = (short*)(ws);             // 196608 B (chunk-major)
    float* bcat = (float*)(ws + 196608);    // 768 B

    const int smem_bytes = 108544;          // 3*32768 + 10240 (>64KB -> dynamic + attribute)
    (void)hipFuncSetAttribute((const void*)fused_kernel,
                              hipFuncAttributeMaxDynamicSharedMemorySize, smem_bytes);

    prep_kernel<<<192, 256, 0, stream>>>(Wk, bk, Wq, bq, Wv, bv, Wt2g, bcat);
    fused_kernel<<<256, 512, smem_bytes, stream>>>(x, Wt2g, bcat, out);
}

// Round 7
// 217.066 us; speedup vs baseline: 1.2434x; 1.0577x over previous
//
#include <hip/hip_runtime.h>
#include <stdint.h>

typedef __attribute__((ext_vector_type(8))) short bf16x8;
typedef __attribute__((ext_vector_type(4))) float f32x4;

#if __has_builtin(__builtin_amdgcn_exp2f)
#define EXP2F(x) __builtin_amdgcn_exp2f(x)
#else
#define EXP2F(x) exp2f(x)
#endif

__device__ __forceinline__ short f2bf(float f) {
    union { float f; uint32_t u; } c; c.f = f;
    return (short)((c.u + 0x7fffu + ((c.u >> 16) & 1u)) >> 16);
}

// async global->LDS 16B/lane: dest = wave-uniform base + lane*16 (m97/m104 semantics)
typedef __attribute__((address_space(1))) void gvoid;
typedef __attribute__((address_space(3))) void lvoid;
__device__ __forceinline__ void async_cp16(const void* g, void* l) {
    __builtin_amdgcn_global_load_lds((gvoid*)g, (lvoid*)l, 16, 0, 0);
}

// ---- prep: Wt2g chunk-major [16 kchunks][192 cols][32 k] bf16 + bcat[192] f32
__global__ void prep_kernel(const float* __restrict__ Wk, const float* __restrict__ bk,
                            const float* __restrict__ Wq, const float* __restrict__ bq,
                            const float* __restrict__ Wv, const float* __restrict__ bv,
                            short* __restrict__ Wt2g, float* __restrict__ bcat) {
    const int col = blockIdx.x;  // 0..191 (0-63=K, 64-127=Q, 128-191=V)
    const float* W; const float* bb; int c0;
    if (col < 64)       { W = Wk; bb = bk; c0 = col; }
    else if (col < 128) { W = Wq; bb = bq; c0 = col - 64; }
    else                { W = Wv; bb = bv; c0 = col - 128; }
    for (int c = threadIdx.x; c < 512; c += blockDim.x)
        Wt2g[(c >> 5) * (192 * 32) + col * 32 + (c & 31)] = f2bf(W[(size_t)c * 64 + c0]);
    if (threadIdx.x == 0) bcat[col] = bb[c0];
}

// ---- fused per-batch kernel, 1024 threads = 16 waves ----
// Wave w owns m-tile w (rows 16w..16w+15) in BOTH phases.
// Phase 1: x chunk (32 KB fp32) + Wt chunk (12 KB bf16) double-buffered in LDS
// via global_load_lds_dwordx4; MFMA from LDS; no VGPR staging of global data.
// Phase 2: all-LDS causal attention (R6-verified machinery, t = wave).
// LDS layout (dynamic, 118784 B):
//   phase 1: xs0 @0 (32K) | xs1 @32768 | ws0 @65536 (12K) | ws1 @77824
//   phase 2: Ks  @0 (32K) | Qs  @32768 | Vts @65536 (32K) | Ps @98304 (20K)
#define PSTR 40

__global__ __launch_bounds__(1024, 4) void fused_kernel(
    const float* __restrict__ x, const short* __restrict__ Wt2g,
    const float* __restrict__ bcat, float* __restrict__ out) {
    extern __shared__ __align__(16) char smem[];

    const int tid = threadIdx.x;
    const int wave = tid >> 6, lane = tid & 63;
    const int quad = lane >> 4, l16 = lane & 15;
    const int b = blockIdx.x;
    const int t = wave;                      // this wave's m-tile / q-tile

    // ================= phase 1: QKV projection =================
    f32x4 acc[12];
#pragma unroll
    for (int i = 0; i < 12; i++) acc[i] = (f32x4){0.f, 0.f, 0.f, 0.f};

    const int xr = lane >> 3;        // row-within-granule (8 rows x 128B = 1KB)
    const int xsl = lane & 7;        // dest 16B slot

    // x granule i covers rows 8i..8i+7; dest slot s holds src slot s^((row&3)<<1)
#define STAGE_X(kc, bufp)                                                           \
    for (int g = 0; g < 2; g++) {                                                   \
        const int i = wave + g * 16;                                                \
        const int r = i * 8 + xr;                                                   \
        const int s = xsl ^ ((r & 3) << 1);                                         \
        async_cp16(x + ((size_t)b * 256 + r) * 512 + (kc) * 32 + s * 4,             \
                   smem + (bufp) * 32768 + i * 1024);                               \
    }
    // Wt granule = 16 cols x 64B = 1KB, plain contiguous copy (waves 0..11)
#define STAGE_W(kc, bufp)                                                           \
    if (wave < 12) {                                                                \
        async_cp16(Wt2g + (size_t)(kc) * 6144 + wave * 512 + lane * 8,              \
                   smem + 65536 + (bufp) * 12288 + wave * 1024);                    \
    }

    STAGE_X(0, 0)
    STAGE_W(0, 0)
    __syncthreads();

    const int axoff = (quad ^ (l16 & 3)) * 8;   // A 32B slot-pair after swizzle
    const int arow = t * 16 + l16;              // local row 0..255
    for (int kc = 0; kc < 16; kc++) {
        const int buf = kc & 1;
        if (kc < 15) { STAGE_X(kc + 1, buf ^ 1) STAGE_W(kc + 1, buf ^ 1) }
        const float* xa = (const float*)(smem + buf * 32768) + arow * 32 + axoff;
        f32x4 u0 = *(const f32x4*)xa, u1 = *(const f32x4*)(xa + 4);
        bf16x8 a;
#pragma unroll
        for (int i = 0; i < 4; i++) { a[i] = f2bf(u0[i]); a[4 + i] = f2bf(u1[i]); }
        const short* wb = (const short*)(smem + 65536 + buf * 12288);
#pragma unroll
        for (int nt = 0; nt < 12; nt++) {
            bf16x8 bfrag = *(const bf16x8*)&wb[(nt * 16 + l16) * 32 + quad * 8];
            acc[nt] = __builtin_amdgcn_mfma_f32_16x16x32_bf16(a, bfrag, acc[nt], 0, 0, 0);
        }
        __syncthreads();
    }

    // ---- epilogue: C-layout (row=quad*4+r, col=l16) -> swizzled phase-2 LDS ----
    short* Ks  = (short*)smem;
    short* Qs  = (short*)(smem + 32768);
    short* Vts = (short*)(smem + 65536);
    short* Ps  = (short*)(smem + 98304);
#pragma unroll
    for (int nt = 0; nt < 12; nt++) {
        const int col = nt * 16 + l16;
        const float bias = bcat[col];
        const int h = col & 63;
#pragma unroll
        for (int r = 0; r < 4; r++) {
            const short v = f2bf(acc[nt][r] + bias);
            const int row = t * 16 + quad * 4 + r;
            if (nt < 4)
                Ks[row * 64 + (((h >> 3) ^ (row & 7)) << 3) + (h & 7)] = v;
            else if (nt < 8)
                Qs[row * 64 + (((h >> 3) ^ (row & 7)) << 3) + (h & 7)] = v;
            else
                Vts[h * 256 + (((row >> 3) ^ (h & 7)) << 3) + (row & 7)] = v;
        }
    }
    __syncthreads();

    // ================= phase 2: causal attention, all-LDS =================
    const float sc2 = 0.125f * 1.44269504088896340736f;  // 1/sqrt(64) * log2(e)
    short* myP = Ps + wave * (16 * PSTR);

    const int qrow = t * 16 + l16;
    const int sw = l16 & 7;
    bf16x8 qf0 = *(const bf16x8*)&Qs[qrow * 64 + ((quad ^ sw) << 3)];
    bf16x8 qf1 = *(const bf16x8*)&Qs[qrow * 64 + (((4 + quad) ^ sw) << 3)];

    f32x4 St[16];
#pragma unroll
    for (int i = 0; i < 16; i++) St[i] = (f32x4){0.f, 0.f, 0.f, 0.f};
#pragma unroll
    for (int nt = 0; nt < 16; nt++) if (nt <= t) {
        const int krow = nt * 16 + l16;
        bf16x8 kf0 = *(const bf16x8*)&Ks[krow * 64 + ((quad ^ sw) << 3)];
        bf16x8 kf1 = *(const bf16x8*)&Ks[krow * 64 + (((4 + quad) ^ sw) << 3)];
        St[nt] = __builtin_amdgcn_mfma_f32_16x16x32_bf16(qf0, kf0, St[nt], 0, 0, 0);
        St[nt] = __builtin_amdgcn_mfma_f32_16x16x32_bf16(qf1, kf1, St[nt], 0, 0, 0);
    }

    // mask + base-2 softmax; C-layout rows = quad*4+r, col = l16
    const int rowq = t * 16 + quad * 4;
    float mx[4], ls[4];
#pragma unroll
    for (int r = 0; r < 4; r++) mx[r] = -3.0e38f;
#pragma unroll
    for (int nt = 0; nt < 16; nt++) if (nt <= t) {
        const int cs = nt * 16 + l16;
#pragma unroll
        for (int r = 0; r < 4; r++) {
            float s = (cs <= rowq + r) ? St[nt][r] * sc2 : -3.0e38f;
            St[nt][r] = s;
            mx[r] = fmaxf(mx[r], s);
        }
    }
#pragma unroll
    for (int d = 1; d < 16; d <<= 1)
#pragma unroll
        for (int r = 0; r < 4; r++)
            mx[r] = fmaxf(mx[r], __shfl_xor(mx[r], d, 64));
#pragma unroll
    for (int r = 0; r < 4; r++) ls[r] = 0.f;
#pragma unroll
    for (int nt = 0; nt < 16; nt++) if (nt <= t) {
#pragma unroll
        for (int r = 0; r < 4; r++) {
            float p = EXP2F(St[nt][r] - mx[r]);
            St[nt][r] = p;                 // St[nt>t] stays 0 == correct P
            ls[r] += p;
        }
    }
#pragma unroll
    for (int d = 1; d < 16; d <<= 1)
#pragma unroll
        for (int r = 0; r < 4; r++)
            ls[r] += __shfl_xor(ls[r], d, 64);

    // O = P V over 32-s chunks; P via wave-local LDS C->A roundtrip
    f32x4 O[4];
#pragma unroll
    for (int i = 0; i < 4; i++) O[i] = (f32x4){0.f, 0.f, 0.f, 0.f};
    const int nch = (t + 2) >> 1;          // ceil((t+1)/2), wave-uniform
#pragma unroll
    for (int c2 = 0; c2 < 8; c2++) if (c2 < nch) {
#pragma unroll
        for (int t2i = 0; t2i < 2; t2i++) {
            const int nt = c2 * 2 + t2i;   // St[nt]=0 beyond diagonal => P=0
#pragma unroll
            for (int r = 0; r < 4; r++)
                myP[(quad * 4 + r) * PSTR + t2i * 16 + l16] = f2bf(St[nt][r]);
        }
        bf16x8 pf = *(const bf16x8*)&myP[l16 * PSTR + quad * 8];
#pragma unroll
        for (int ht = 0; ht < 4; ht++) {
            const int h = ht * 16 + l16;
            bf16x8 vf = *(const bf16x8*)&Vts[h * 256 + (((c2 * 4 + quad) ^ (h & 7)) << 3)];
            O[ht] = __builtin_amdgcn_mfma_f32_16x16x32_bf16(pf, vf, O[ht], 0, 0, 0);
        }
    }

    float rls[4];
#pragma unroll
    for (int r = 0; r < 4; r++) rls[r] = 1.0f / ls[r];
#pragma unroll
    for (int ht = 0; ht < 4; ht++)
#pragma unroll
        for (int r = 0; r < 4; r++)
            out[((size_t)b * 256 + rowq + r) * 64 + ht * 16 + l16] = O[ht][r] * rls[r];
#undef STAGE_X
#undef STAGE_W
}

extern "C" void kernel_launch(void* const* d_in, const int* in_sizes, int n_in,
                              void* d_out, int out_size, void* d_ws, size_t ws_size,
                              hipStream_t stream) {
    const float* x  = (const float*)d_in[0];
    const float* Wk = (const float*)d_in[1];
    const float* bk = (const float*)d_in[2];
    const float* Wq = (const float*)d_in[3];
    const float* bq = (const float*)d_in[4];
    const float* Wv = (const float*)d_in[5];
    const float* bv = (const float*)d_in[6];
    float* out = (float*)d_out;

    char* ws = (char*)d_ws;
    short* Wt2g = (short*)(ws);             // 196608 B (chunk-major)
    float* bcat = (float*)(ws + 196608);    // 768 B

    const int smem_bytes = 118784;          // >64KB -> dynamic + attribute
    (void)hipFuncSetAttribute((const void*)fused_kernel,
                              hipFuncAttributeMaxDynamicSharedMemorySize, smem_bytes);

    prep_kernel<<<192, 256, 0, stream>>>(Wk, bk, Wq, bq, Wv, bv, Wt2g, bcat);
    fused_kernel<<<256, 1024, smem_bytes, stream>>>(x, Wt2g, bcat, out);
}